// Round 16
// baseline (133.867 us; speedup 1.0000x reference)
//
#include <hip/hip_runtime.h>

#define N_NODES 50000
#define N_EDGES 800000
#define D 64
#define KBINS 782            // 64-node bins (tgt>>6); 782*64 = 50048 >= N
#define CCAP64 1280          // edges/bin: mean 1024, sigma 32 -> +8 sigma
#define BIN_NODES 64         // k2 nodes per block
#define NODE_CAP 64          // deg ~ Poisson(16); P(>64) ~ 1e-18
#define BROW 72              // u16 stride per node bucket in LDS (144 B)
#define KA_BLOCKS 256        // ONE KA block per CU (800000/256 = 3125 exact)
#define KA_EDGES 3125
#define KA_ITERS 13          // ceil(3125/256)
#define GEMV_BLOCKS 782      // 64 rows per block (merge@W_tr^T via MFMA)
#define CVT_BLOCKS 3125
#define K1_BLOCKS (KA_BLOCKS + GEMV_BLOCKS + CVT_BLOCKS)
#define SCAN_W 5             // ceil(CCAP64/256) scan words per thread
#define MAGIC 0x7A3F19E5u    // flag value; not byte-replicated (poison-safe)
#define ZROW 50000u          // zero row in data16 (sentinel gather target)
#define CPAD 16              // gCur counter stride: 16 ints = 64 B = 1 line
#define GCUR_INTS (KBINS * CPAD + 256)   // counters + flag region
#define FLAG_IDX (KBINS * CPAD)          // flag slot (own line)

typedef __attribute__((ext_vector_type(8))) short short8t;   // 8 bf16 (4 VGPR)
typedef __attribute__((ext_vector_type(4))) float f32x4;     // MFMA acc

__device__ __forceinline__ unsigned int f2bf(float f) {
    unsigned int u = __builtin_bit_cast(unsigned int, f);
    return (u + 0x7fffu + ((u >> 16) & 1u)) >> 16;
}
__device__ __forceinline__ float bflo(unsigned int v) {
    return __builtin_bit_cast(float, v << 16);
}
__device__ __forceinline__ float bfhi(unsigned int v) {
    return __builtin_bit_cast(float, v & 0xffff0000u);
}
__device__ __forceinline__ short8t pack8(float4 a, float4 b) {
    union { uint4 u; short8t s; } cv;
    cv.u.x = f2bf(a.x) | (f2bf(a.y) << 16);
    cv.u.y = f2bf(a.z) | (f2bf(a.w) << 16);
    cv.u.z = f2bf(b.x) | (f2bf(b.y) << 16);
    cv.u.w = f2bf(b.z) | (f2bf(b.w) << 16);
    return cv.s;
}
// LDS bf16 tile [64 rows][64 cols] (128 B/row) with XOR swizzle (G4).
__device__ __forceinline__ short8t ld_tile(const unsigned short* t, int row, int kb) {
    int addr = (row * 128 + kb) ^ ((row & 7) << 4);
    union { uint4 u; short8t s; } cv;
    cv.u = *(const uint4*)((const char*)t + addr);
    return cv.s;
}
__device__ __forceinline__ void st_tile(unsigned short* t, int row, int kb, uint4 v) {
    int addr = (row * 128 + kb) ^ ((row & 7) << 4);
    *(uint4*)((char*)t + addr) = v;
}

// ---------------------------------------------------------------------------
// ROUND-27 = R12 + gCur CACHE-LINE PADDING (the one untouched >=3us lump).
// R15 (R12 verbatim rerun) calibrated noise at +-2us. Mechanism here: gCur's
// 782 contiguous counters span ~48 L2 lines; the reserve phase funnels ~196K
// device-scope atomics (256 blocks x ~766 non-empty bins) through those few
// lines -- ~8-10us during which every KA block stalls between its two
// syncthreads. Padding each counter to its own 64B line (stride 16 ints)
// spreads the same-address chains across all L2 channels. Cost: <<4 on the
// index in 3 places + 50KB zeroing by block 0 (~1us, overlapped).
// Everything else is R12 verbatim.
// ---------------------------------------------------------------------------
__global__ __launch_bounds__(256) void k1_kernel(
        const float* __restrict__ data,
        const float* __restrict__ merge,
        const int* __restrict__ src, const int* __restrict__ tgt,
        const float* __restrict__ W_tr, const float* __restrict__ b_tr,
        unsigned short* __restrict__ data16,
        int* __restrict__ gCur, unsigned int* __restrict__ gPairs,
        float* __restrict__ outv) {
    __shared__ int hist[KBINS], rbase[KBINS], cur2[KBINS];          // 9.4 KB
    __shared__ __align__(16) unsigned short mtile[64 * 64];         // 8 KB
    int b = blockIdx.x;
    int tid = threadIdx.x;
    if (b < KA_BLOCKS) {
        int eb = b * KA_EDGES;           // n == KA_EDGES always (exact div)
        // block 0: zero gCur at the coherence point, then publish flag
        if (b == 0) {
            for (int i = tid; i < GCUR_INTS; i += 256) atomicExch(&gCur[i], 0);
            __threadfence();
            __syncthreads();
            if (tid == 0)
                atomicExch((unsigned int*)&gCur[FLAG_IDX], MAGIC);
        }
        for (int i = tid; i < KBINS; i += 256) { hist[i] = 0; cur2[i] = 0; }
        // ---- phase A: all loads issued unconditionally (clamped) ----------
        int tg[KA_ITERS], sr[KA_ITERS];
#pragma unroll
        for (int j = 0; j < KA_ITERS; j++) {
            int i = j * 256 + tid;
            int ic = i < KA_EDGES ? i : 0;
            tg[j] = tgt[eb + ic];
            sr[j] = src[eb + ic];
        }
        __syncthreads();                 // hist zero visible
        // ---- phase B: register-only hist pass -----------------------------
        unsigned int pe[KA_ITERS];
#pragma unroll
        for (int j = 0; j < KA_ITERS; j++) {
            int i = j * 256 + tid;
            pe[j] = ((unsigned int)tg[j] << 16) | (unsigned int)sr[j];
            if (i < KA_EDGES) atomicAdd(&hist[tg[j] >> 6], 1);
        }
        __syncthreads();
        // ---- wait for gCur zeroing (flag), then reserve runs --------------
        // padded counters: bin c lives at gCur[c*CPAD] (own 64B line) so the
        // ~196K reserve atomics pipeline across all L2 channels.
        if (tid == 0) {
            while (atomicAdd((unsigned int*)&gCur[FLAG_IDX], 0u) != MAGIC) {}
        }
        __syncthreads();
        for (int i = tid; i < KBINS; i += 256)
            if (hist[i] > 0)
                rbase[i] = atomicAdd(&gCur[i * CPAD], hist[i]);
        __syncthreads();
        // ---- phase C: scatter from registers ------------------------------
#pragma unroll
        for (int j = 0; j < KA_ITERS; j++) {
            int i = j * 256 + tid;
            if (i < KA_EDGES) {
                unsigned int p = pe[j];
                int c = p >> 22;                        // tgt>>6
                int pos = rbase[c] + atomicAdd(&cur2[c], 1);
                if (pos < CCAP64) gPairs[(size_t)c * CCAP64 + pos] = p;
            }
        }
    } else if (b < KA_BLOCKS + GEMV_BLOCKS) {
        // ---- skip GEMM: out[64 rows] = merge@W_tr^T + b_tr (MFMA) ---------
        int gb = b - KA_BLOCKS;
        int lane = tid & 63;
        int w = tid >> 6;
        int rowBase = gb * 64;

        // stage merge tile -> bf16 LDS (swizzled): thread (r=tid>>2, q=tid&3)
        {
            int r = tid >> 2, q = tid & 3;
            int gr = rowBase + r; if (gr >= N_NODES) gr = N_NODES - 1;
            const float4* mp = (const float4*)(merge + (size_t)gr * D + q * 16);
            float4 f0 = mp[0], f1 = mp[1], f2 = mp[2], f3 = mp[3];
            union { short8t s; uint4 u; } c0, c1;
            c0.s = pack8(f0, f1); c1.s = pack8(f2, f3);
            st_tile(mtile, r, q * 32, c0.u);
            st_tile(mtile, r, q * 32 + 16, c1.u);
        }
        // B-frags: W_tr rows 16t+(lane&15), k floats (lane>>4)*8 + s*32
        short8t bfr[4][2];
        float bias[4];
#pragma unroll
        for (int t = 0; t < 4; t++) {
            int wrow = 16 * t + (lane & 15);
            bias[t] = b_tr[wrow];
#pragma unroll
            for (int s = 0; s < 2; s++) {
                const float4* wp = (const float4*)(W_tr + (size_t)wrow * D
                                                   + (lane >> 4) * 8 + s * 32);
                bfr[t][s] = pack8(wp[0], wp[1]);
            }
        }
        __syncthreads();

        f32x4 acc[4] = {{0,0,0,0},{0,0,0,0},{0,0,0,0},{0,0,0,0}};
#pragma unroll
        for (int s = 0; s < 2; s++) {
            short8t a = ld_tile(mtile, 16 * w + (lane & 15),
                                (lane >> 4) * 16 + s * 64);
#pragma unroll
            for (int t = 0; t < 4; t++)
                acc[t] = __builtin_amdgcn_mfma_f32_16x16x32_bf16(
                    a, bfr[t][s], acc[t], 0, 0, 0);
        }
        // C/D: row=(lane>>4)*4+j (node within strip), col=lane&15
#pragma unroll
        for (int t = 0; t < 4; t++) {
            int cl = 16 * t + (lane & 15);
#pragma unroll
            for (int j = 0; j < 4; j++) {
                int node = rowBase + 16 * w + (lane >> 4) * 4 + j;
                if (node < N_NODES)
                    outv[(size_t)node * D + cl] = acc[t][j] + bias[t];
            }
        }
    } else {
        int i = (b - KA_BLOCKS - GEMV_BLOCKS) * 256 + tid;   // float4 index
        float4 d = ((const float4*)data)[i];
        uint2 v;
        v.x = f2bf(d.x) | (f2bf(d.y) << 16);
        v.y = f2bf(d.z) | (f2bf(d.w) << 16);
        ((uint2*)data16)[i] = v;
        // first CVT block also zeroes the sentinel row (index ZROW)
        if (b == KA_BLOCKS + GEMV_BLOCKS && tid < 16) {
            uint2 z; z.x = 0u; z.y = 0u;
            ((uint2*)(data16 + (size_t)ZROW * D))[tid] = z;
        }
    }
}

// ---------------------------------------------------------------------------
// K2: one block per 64-node bin. Buckets pre-filled with ZROW; gather is
// mask-free; batch1 (slots 16..31) skipped when dgc <= 16+par*4 (exact:
// those slots are all ZROW pad). MFMA epilogue: out = relu(h@W_lin^T + skip).
// ---------------------------------------------------------------------------
__global__ __launch_bounds__(256) void k2_kernel(
        const float* __restrict__ data,
        const unsigned short* __restrict__ data16,
        const int* __restrict__ gCur,
        const unsigned int* __restrict__ gPairs,
        const float* __restrict__ W_lin,
        float* __restrict__ out) {
    __shared__ __align__(16) unsigned short lbkt[BIN_NODES * BROW];  // 9 KB
    __shared__ int lcur[BIN_NODES];
    __shared__ __align__(16) unsigned short hb[BIN_NODES * D];       // 8 KB bf16

    int tid = threadIdx.x;
    int lane = tid & 63;
    int bin = blockIdx.x;
    int nodeBase = bin * BIN_NODES;

    // pre-fill bucket slots 0..63 of every node with ZROW (sentinel).
    {
        uint4 zr; zr.x = zr.y = zr.z = zr.w = (ZROW & 0xffffu) * 0x10001u;
#pragma unroll
        for (int r = 0; r < 2; r++) {
            int c = r * 256 + tid;               // 512 chunks total
            *(uint4*)((char*)lbkt + (c >> 3) * (BROW * 2) + (c & 7) * 16) = zr;
        }
        if (tid < BIN_NODES) lcur[tid] = 0;
    }
    __syncthreads();

    // ---- scan: own bin, unconditional clamped loads, no filter ------------
    int cnt = gCur[bin * CPAD]; if (cnt > CCAP64) cnt = CCAP64;
    const unsigned int* cp = gPairs + (size_t)bin * CCAP64;
    unsigned int pw[SCAN_W];
#pragma unroll
    for (int j = 0; j < SCAN_W; j++) {
        int i = j * 256 + tid;
        pw[j] = cp[i < cnt ? i : 0];
    }
#pragma unroll
    for (int j = 0; j < SCAN_W; j++) {
        int i = j * 256 + tid;
        unsigned int pr = pw[j];
        if (i < cnt) {
            int nd = (pr >> 16) & 63;            // local node within bin
            int pos = atomicAdd(&lcur[nd], 1);
            if (pos < NODE_CAP)
                lbkt[nd * BROW + pos] = (unsigned short)(pr & 0xffffu);
        }
    }
    __syncthreads();

    // ---- gather: group g=tid>>3 (0..31), lane ln=tid&7, par=g&1 -----------
    int g = tid >> 3;
    int ln = tid & 7;
    int par = g & 1;
    int nsel = g >> 1;                           // 0..15

#pragma unroll 1
    for (int q = 0; q < 4; q++) {
        int node = q * 16 + nsel;                // 0..63
        int n = nodeBase + node;
        int valid = n < N_NODES;
        int dg = lcur[node];
        int dgc = dg < NODE_CAP ? dg : NODE_CAP;

        const float4* orow = (const float4*)(data + (size_t)(valid ? n : 0) * D + 8 * ln);
        float4 o0 = orow[0], o1 = orow[1];

        const uint2* idxp = (const uint2*)(lbkt + node * BROW + par * 4);
        uint2 iw0 = idxp[0], iw1 = idxp[2], iw2 = idxp[4], iw3 = idxp[6];

        float af[4][8];
#pragma unroll
        for (int ch = 0; ch < 4; ch++)
#pragma unroll
            for (int k = 0; k < 8; k++) af[ch][k] = 0.f;

        // ---- batch 0: slots it=0,1 (covers deg<=16) -- unconditional ------
        {
            unsigned int idx[8];
            unsigned int iww[4] = { iw0.x, iw0.y, iw1.x, iw1.y };
#pragma unroll
            for (int qq = 0; qq < 4; qq++) {
                idx[qq * 2]     = iww[qq] & 0xffffu;
                idx[qq * 2 + 1] = iww[qq] >> 16;
            }
            uint4 v[8];
#pragma unroll
            for (int k = 0; k < 8; k++)
                v[k] = *(const uint4*)(data16 + (size_t)idx[k] * D + 8 * ln);
#pragma unroll
            for (int k = 0; k < 8; k++) {
                int ch = k & 3;
                af[ch][0] += bflo(v[k].x); af[ch][1] += bfhi(v[k].x);
                af[ch][2] += bflo(v[k].y); af[ch][3] += bfhi(v[k].y);
                af[ch][4] += bflo(v[k].z); af[ch][5] += bfhi(v[k].z);
                af[ch][6] += bflo(v[k].w); af[ch][7] += bfhi(v[k].w);
            }
        }
        // ---- batch 1: slots it=2,3 -- group-uniform guard (43% taken) -----
        if (16 + par * 4 < dgc) {
            unsigned int idx[8];
            unsigned int iww[4] = { iw2.x, iw2.y, iw3.x, iw3.y };
#pragma unroll
            for (int qq = 0; qq < 4; qq++) {
                idx[qq * 2]     = iww[qq] & 0xffffu;
                idx[qq * 2 + 1] = iww[qq] >> 16;
            }
            uint4 v[8];
#pragma unroll
            for (int k = 0; k < 8; k++)
                v[k] = *(const uint4*)(data16 + (size_t)idx[k] * D + 8 * ln);
#pragma unroll
            for (int k = 0; k < 8; k++) {
                int ch = k & 3;
                af[ch][0] += bflo(v[k].x); af[ch][1] += bfhi(v[k].x);
                af[ch][2] += bflo(v[k].y); af[ch][3] += bfhi(v[k].y);
                af[ch][4] += bflo(v[k].z); af[ch][5] += bfhi(v[k].z);
                af[ch][6] += bflo(v[k].w); af[ch][7] += bfhi(v[k].w);
            }
        }
        // tail: deg > 32 (~6 nodes in the whole graph); pad slots are ZROW
        int nIt = (dgc + 7) >> 3;
        for (int it = 4; it < nIt; it++) {
            uint2 iw = idxp[it * 2];
            unsigned int jdx[4] = { iw.x & 0xffffu, iw.x >> 16,
                                    iw.y & 0xffffu, iw.y >> 16 };
            uint4 vv[4];
#pragma unroll
            for (int k = 0; k < 4; k++)
                vv[k] = *(const uint4*)(data16 + (size_t)jdx[k] * D + 8 * ln);
#pragma unroll
            for (int k = 0; k < 4; k++) {
                af[k][0] += bflo(vv[k].x); af[k][1] += bfhi(vv[k].x);
                af[k][2] += bflo(vv[k].y); af[k][3] += bfhi(vv[k].y);
                af[k][4] += bflo(vv[k].z); af[k][5] += bfhi(vv[k].z);
                af[k][6] += bflo(vv[k].w); af[k][7] += bfhi(vv[k].w);
            }
        }

        float sv[8];
#pragma unroll
        for (int k = 0; k < 8; k++)
            sv[k] = (af[0][k] + af[1][k]) + (af[2][k] + af[3][k]);
#pragma unroll
        for (int k = 0; k < 8; k++) sv[k] += __shfl_xor(sv[k], 8);   // parities

        if (par == 0) {
            float inv = dg > 0 ? 1.0f / (float)dg : 0.0f;
            float msk = dg > 0 ? 1.0f : 0.0f;
            float4 h0, h1;
            h0.x = (o0.x - sv[0] * inv) * msk; h0.y = (o0.y - sv[1] * inv) * msk;
            h0.z = (o0.z - sv[2] * inv) * msk; h0.w = (o0.w - sv[3] * inv) * msk;
            h1.x = (o1.x - sv[4] * inv) * msk; h1.y = (o1.y - sv[5] * inv) * msk;
            h1.z = (o1.z - sv[6] * inv) * msk; h1.w = (o1.w - sv[7] * inv) * msk;
            // h row -> bf16 tile, cols 8ln..8ln+7 (16-byte block ln), swizzled
            union { short8t s; uint4 u; } hv;
            hv.s = pack8(h0, h1);
            st_tile(hb, node, ln * 16, hv.u);
        }
    }

    // ---- MFMA epilogue operand prefetch (latency hidden under barrier) ----
    int w = tid >> 6;
    short8t bfr[4][2];
#pragma unroll
    for (int t = 0; t < 4; t++)
#pragma unroll
        for (int s = 0; s < 2; s++) {
            const float4* wp = (const float4*)(W_lin
                + (size_t)(16 * t + (lane & 15)) * D + (lane >> 4) * 8 + s * 32);
            bfr[t][s] = pack8(wp[0], wp[1]);
        }
    float oldv[4][4];
#pragma unroll
    for (int t = 0; t < 4; t++) {
        int cl = 16 * t + (lane & 15);
#pragma unroll
        for (int j = 0; j < 4; j++) {
            int node = nodeBase + 16 * w + (lane >> 4) * 4 + j;
            oldv[t][j] = out[(size_t)(node < N_NODES ? node : 0) * D + cl];
        }
    }
    __syncthreads();

    // ---- MFMA: wave w -> rows 16w..16w+15; out = relu(h@W_lin^T + skip) ---
    f32x4 acc[4] = {{0,0,0,0},{0,0,0,0},{0,0,0,0},{0,0,0,0}};
#pragma unroll
    for (int s = 0; s < 2; s++) {
        short8t a = ld_tile(hb, 16 * w + (lane & 15), (lane >> 4) * 16 + s * 64);
#pragma unroll
        for (int t = 0; t < 4; t++)
            acc[t] = __builtin_amdgcn_mfma_f32_16x16x32_bf16(
                a, bfr[t][s], acc[t], 0, 0, 0);
    }
#pragma unroll
    for (int t = 0; t < 4; t++) {
        int cl = 16 * t + (lane & 15);
#pragma unroll
        for (int j = 0; j < 4; j++) {
            int node = nodeBase + 16 * w + (lane >> 4) * 4 + j;
            if (node < N_NODES) {
                float o = acc[t][j] + oldv[t][j];
                out[(size_t)node * D + cl] = o > 0.f ? o : 0.f;
            }
        }
    }
}

extern "C" void kernel_launch(void* const* d_in, const int* in_sizes, int n_in,
                              void* d_out, int out_size, void* d_ws, size_t ws_size,
                              hipStream_t stream) {
    const float* data  = (const float*)d_in[0];
    const float* merge = (const float*)d_in[1];
    const int*   src   = (const int*)d_in[2];
    const int*   tgt   = (const int*)d_in[3];
    // d_in[4]=W_lin, d_in[5]=b_lin (cancels in lap), d_in[6]=W_tr, d_in[7]=b_tr
    const float* W_lin = (const float*)d_in[4];
    const float* W_tr  = (const float*)d_in[6];
    const float* b_tr  = (const float*)d_in[7];
    float* out = (float*)d_out;

    // Workspace: gCur[782*16 + 256 i32: counter c at c*16, flag at 782*16]
    //            (50.2 KB) | gPairs[782*1280 u32] (4.0 MB)
    //            | data16[(N+1)*D bf16] (6.4 MB, row 50000 = zeros)
    char* ws = (char*)d_ws;
    size_t o = 0;
    int*            gCur   = (int*)(ws + o);            o += (size_t)GCUR_INTS * 4;
    unsigned int*   gPairs = (unsigned int*)(ws + o);   o += (size_t)KBINS * CCAP64 * 4;
    unsigned short* data16 = (unsigned short*)(ws + o); o += (size_t)(N_NODES + 1) * D * 2;

    // no memset: k1 block 0 zeroes gCur in-kernel (flag handshake)

    k1_kernel<<<K1_BLOCKS, 256, 0, stream>>>(
        data, merge, src, tgt, W_tr, b_tr, data16, gCur, gPairs, out);

    k2_kernel<<<KBINS, 256, 0, stream>>>(
        data, data16, gCur, gPairs, W_lin, out);
}

// Round 17
// 127.565 us; speedup vs baseline: 1.0494x; 1.0494x over previous
//
#include <hip/hip_runtime.h>

#define N_NODES 50000
#define N_EDGES 800000
#define D 64
#define KBINS 782            // 64-node bins (tgt>>6); 782*64 = 50048 >= N
#define CCAP64 1280          // edges/bin: mean 1024, sigma 32 -> +8 sigma
#define BIN_NODES 64         // k2 nodes per block
#define NODE_CAP 64          // deg ~ Poisson(16); P(>64) ~ 1e-18
#define BROW 72              // u16 stride per node bucket in LDS (144 B)
#define KA_BLOCKS 256        // ONE KA block per CU (800000/256 = 3125 exact)
#define KA_EDGES 3125
#define KA_ITERS 13          // ceil(3125/256)
#define GEMV_BLOCKS 782      // 64 rows per block (merge@W_tr^T via MFMA)
#define CVT_BLOCKS 3125
#define K1_BLOCKS (KA_BLOCKS + GEMV_BLOCKS + CVT_BLOCKS)
#define SCAN_W 5             // ceil(CCAP64/256) scan words per thread
#define MAGIC 0x7A3F19E5u    // flag value; not byte-replicated (poison-safe)
#define ZROW 50000u          // zero row in data16 (sentinel gather target)

typedef __attribute__((ext_vector_type(8))) short short8t;   // 8 bf16 (4 VGPR)
typedef __attribute__((ext_vector_type(4))) float f32x4;     // MFMA acc

__device__ __forceinline__ unsigned int f2bf(float f) {
    unsigned int u = __builtin_bit_cast(unsigned int, f);
    return (u + 0x7fffu + ((u >> 16) & 1u)) >> 16;
}
__device__ __forceinline__ float bflo(unsigned int v) {
    return __builtin_bit_cast(float, v << 16);
}
__device__ __forceinline__ float bfhi(unsigned int v) {
    return __builtin_bit_cast(float, v & 0xffff0000u);
}
__device__ __forceinline__ short8t pack8(float4 a, float4 b) {
    union { uint4 u; short8t s; } cv;
    cv.u.x = f2bf(a.x) | (f2bf(a.y) << 16);
    cv.u.y = f2bf(a.z) | (f2bf(a.w) << 16);
    cv.u.z = f2bf(b.x) | (f2bf(b.y) << 16);
    cv.u.w = f2bf(b.z) | (f2bf(b.w) << 16);
    return cv.s;
}
// LDS bf16 tile [64 rows][64 cols] (128 B/row) with XOR swizzle (G4).
__device__ __forceinline__ short8t ld_tile(const unsigned short* t, int row, int kb) {
    int addr = (row * 128 + kb) ^ ((row & 7) << 4);
    union { uint4 u; short8t s; } cv;
    cv.u = *(const uint4*)((const char*)t + addr);
    return cv.s;
}
__device__ __forceinline__ void st_tile(unsigned short* t, int row, int kb, uint4 v) {
    int addr = (row * 128 + kb) ^ ((row & 7) << 4);
    *(uint4*)((char*)t + addr) = v;
}

// ---------------------------------------------------------------------------
// FINAL = ROUND-23 (R12) VERBATIM -- verified best (128.6 us; rerun 130.4,
// noise +-2us). R16's gCur padding regressed +3.5us (block-0 zeroing delayed
// the flag publish; padding win ~= 0 -> contention model falsified). All
// remaining >=3us hypotheses tested and falsified. Practical plateau.
// ---------------------------------------------------------------------------
__global__ __launch_bounds__(256) void k1_kernel(
        const float* __restrict__ data,
        const float* __restrict__ merge,
        const int* __restrict__ src, const int* __restrict__ tgt,
        const float* __restrict__ W_tr, const float* __restrict__ b_tr,
        unsigned short* __restrict__ data16,
        int* __restrict__ gCur, unsigned int* __restrict__ gPairs,
        float* __restrict__ outv) {
    __shared__ int hist[KBINS], rbase[KBINS], cur2[KBINS];          // 9.4 KB
    __shared__ __align__(16) unsigned short mtile[64 * 64];         // 8 KB
    int b = blockIdx.x;
    int tid = threadIdx.x;
    if (b < KA_BLOCKS) {
        int eb = b * KA_EDGES;           // n == KA_EDGES always (exact div)
        if (b == 0) {
            for (int i = tid; i < 1024; i += 256) atomicExch(&gCur[i], 0);
            __threadfence();
            __syncthreads();
            if (tid == 0)
                atomicExch((unsigned int*)&gCur[1023], MAGIC);
        }
        for (int i = tid; i < KBINS; i += 256) { hist[i] = 0; cur2[i] = 0; }
        int tg[KA_ITERS], sr[KA_ITERS];
#pragma unroll
        for (int j = 0; j < KA_ITERS; j++) {
            int i = j * 256 + tid;
            int ic = i < KA_EDGES ? i : 0;
            tg[j] = tgt[eb + ic];
            sr[j] = src[eb + ic];
        }
        __syncthreads();
        unsigned int pe[KA_ITERS];
#pragma unroll
        for (int j = 0; j < KA_ITERS; j++) {
            int i = j * 256 + tid;
            pe[j] = ((unsigned int)tg[j] << 16) | (unsigned int)sr[j];
            if (i < KA_EDGES) atomicAdd(&hist[tg[j] >> 6], 1);
        }
        __syncthreads();
        if (tid == 0) {
            while (atomicAdd((unsigned int*)&gCur[1023], 0u) != MAGIC) {}
        }
        __syncthreads();
        for (int i = tid; i < KBINS; i += 256)
            if (hist[i] > 0)
                rbase[i] = atomicAdd(&gCur[i], hist[i]);
        __syncthreads();
#pragma unroll
        for (int j = 0; j < KA_ITERS; j++) {
            int i = j * 256 + tid;
            if (i < KA_EDGES) {
                unsigned int p = pe[j];
                int c = p >> 22;                        // tgt>>6
                int pos = rbase[c] + atomicAdd(&cur2[c], 1);
                if (pos < CCAP64) gPairs[(size_t)c * CCAP64 + pos] = p;
            }
        }
    } else if (b < KA_BLOCKS + GEMV_BLOCKS) {
        int gb = b - KA_BLOCKS;
        int lane = tid & 63;
        int w = tid >> 6;
        int rowBase = gb * 64;
        {
            int r = tid >> 2, q = tid & 3;
            int gr = rowBase + r; if (gr >= N_NODES) gr = N_NODES - 1;
            const float4* mp = (const float4*)(merge + (size_t)gr * D + q * 16);
            float4 f0 = mp[0], f1 = mp[1], f2 = mp[2], f3 = mp[3];
            union { short8t s; uint4 u; } c0, c1;
            c0.s = pack8(f0, f1); c1.s = pack8(f2, f3);
            st_tile(mtile, r, q * 32, c0.u);
            st_tile(mtile, r, q * 32 + 16, c1.u);
        }
        short8t bfr[4][2];
        float bias[4];
#pragma unroll
        for (int t = 0; t < 4; t++) {
            int wrow = 16 * t + (lane & 15);
            bias[t] = b_tr[wrow];
#pragma unroll
            for (int s = 0; s < 2; s++) {
                const float4* wp = (const float4*)(W_tr + (size_t)wrow * D
                                                   + (lane >> 4) * 8 + s * 32);
                bfr[t][s] = pack8(wp[0], wp[1]);
            }
        }
        __syncthreads();

        f32x4 acc[4] = {{0,0,0,0},{0,0,0,0},{0,0,0,0},{0,0,0,0}};
#pragma unroll
        for (int s = 0; s < 2; s++) {
            short8t a = ld_tile(mtile, 16 * w + (lane & 15),
                                (lane >> 4) * 16 + s * 64);
#pragma unroll
            for (int t = 0; t < 4; t++)
                acc[t] = __builtin_amdgcn_mfma_f32_16x16x32_bf16(
                    a, bfr[t][s], acc[t], 0, 0, 0);
        }
#pragma unroll
        for (int t = 0; t < 4; t++) {
            int cl = 16 * t + (lane & 15);
#pragma unroll
            for (int j = 0; j < 4; j++) {
                int node = rowBase + 16 * w + (lane >> 4) * 4 + j;
                if (node < N_NODES)
                    outv[(size_t)node * D + cl] = acc[t][j] + bias[t];
            }
        }
    } else {
        int i = (b - KA_BLOCKS - GEMV_BLOCKS) * 256 + tid;   // float4 index
        float4 d = ((const float4*)data)[i];
        uint2 v;
        v.x = f2bf(d.x) | (f2bf(d.y) << 16);
        v.y = f2bf(d.z) | (f2bf(d.w) << 16);
        ((uint2*)data16)[i] = v;
        if (b == KA_BLOCKS + GEMV_BLOCKS && tid < 16) {
            uint2 z; z.x = 0u; z.y = 0u;
            ((uint2*)(data16 + (size_t)ZROW * D))[tid] = z;
        }
    }
}

__global__ __launch_bounds__(256) void k2_kernel(
        const float* __restrict__ data,
        const unsigned short* __restrict__ data16,
        const int* __restrict__ gCur,
        const unsigned int* __restrict__ gPairs,
        const float* __restrict__ W_lin,
        float* __restrict__ out) {
    __shared__ __align__(16) unsigned short lbkt[BIN_NODES * BROW];  // 9 KB
    __shared__ int lcur[BIN_NODES];
    __shared__ __align__(16) unsigned short hb[BIN_NODES * D];       // 8 KB bf16

    int tid = threadIdx.x;
    int lane = tid & 63;
    int bin = blockIdx.x;
    int nodeBase = bin * BIN_NODES;

    {
        uint4 zr; zr.x = zr.y = zr.z = zr.w = (ZROW & 0xffffu) * 0x10001u;
#pragma unroll
        for (int r = 0; r < 2; r++) {
            int c = r * 256 + tid;               // 512 chunks total
            *(uint4*)((char*)lbkt + (c >> 3) * (BROW * 2) + (c & 7) * 16) = zr;
        }
        if (tid < BIN_NODES) lcur[tid] = 0;
    }
    __syncthreads();

    int cnt = gCur[bin]; if (cnt > CCAP64) cnt = CCAP64;
    const unsigned int* cp = gPairs + (size_t)bin * CCAP64;
    unsigned int pw[SCAN_W];
#pragma unroll
    for (int j = 0; j < SCAN_W; j++) {
        int i = j * 256 + tid;
        pw[j] = cp[i < cnt ? i : 0];
    }
#pragma unroll
    for (int j = 0; j < SCAN_W; j++) {
        int i = j * 256 + tid;
        unsigned int pr = pw[j];
        if (i < cnt) {
            int nd = (pr >> 16) & 63;            // local node within bin
            int pos = atomicAdd(&lcur[nd], 1);
            if (pos < NODE_CAP)
                lbkt[nd * BROW + pos] = (unsigned short)(pr & 0xffffu);
        }
    }
    __syncthreads();

    int g = tid >> 3;
    int ln = tid & 7;
    int par = g & 1;
    int nsel = g >> 1;                           // 0..15

#pragma unroll 1
    for (int q = 0; q < 4; q++) {
        int node = q * 16 + nsel;                // 0..63
        int n = nodeBase + node;
        int valid = n < N_NODES;
        int dg = lcur[node];
        int dgc = dg < NODE_CAP ? dg : NODE_CAP;

        const float4* orow = (const float4*)(data + (size_t)(valid ? n : 0) * D + 8 * ln);
        float4 o0 = orow[0], o1 = orow[1];

        const uint2* idxp = (const uint2*)(lbkt + node * BROW + par * 4);
        uint2 iw0 = idxp[0], iw1 = idxp[2], iw2 = idxp[4], iw3 = idxp[6];

        float af[4][8];
#pragma unroll
        for (int ch = 0; ch < 4; ch++)
#pragma unroll
            for (int k = 0; k < 8; k++) af[ch][k] = 0.f;

        {
            unsigned int idx[8];
            unsigned int iww[4] = { iw0.x, iw0.y, iw1.x, iw1.y };
#pragma unroll
            for (int qq = 0; qq < 4; qq++) {
                idx[qq * 2]     = iww[qq] & 0xffffu;
                idx[qq * 2 + 1] = iww[qq] >> 16;
            }
            uint4 v[8];
#pragma unroll
            for (int k = 0; k < 8; k++)
                v[k] = *(const uint4*)(data16 + (size_t)idx[k] * D + 8 * ln);
#pragma unroll
            for (int k = 0; k < 8; k++) {
                int ch = k & 3;
                af[ch][0] += bflo(v[k].x); af[ch][1] += bfhi(v[k].x);
                af[ch][2] += bflo(v[k].y); af[ch][3] += bfhi(v[k].y);
                af[ch][4] += bflo(v[k].z); af[ch][5] += bfhi(v[k].z);
                af[ch][6] += bflo(v[k].w); af[ch][7] += bfhi(v[k].w);
            }
        }
        if (16 + par * 4 < dgc) {
            unsigned int idx[8];
            unsigned int iww[4] = { iw2.x, iw2.y, iw3.x, iw3.y };
#pragma unroll
            for (int qq = 0; qq < 4; qq++) {
                idx[qq * 2]     = iww[qq] & 0xffffu;
                idx[qq * 2 + 1] = iww[qq] >> 16;
            }
            uint4 v[8];
#pragma unroll
            for (int k = 0; k < 8; k++)
                v[k] = *(const uint4*)(data16 + (size_t)idx[k] * D + 8 * ln);
#pragma unroll
            for (int k = 0; k < 8; k++) {
                int ch = k & 3;
                af[ch][0] += bflo(v[k].x); af[ch][1] += bfhi(v[k].x);
                af[ch][2] += bflo(v[k].y); af[ch][3] += bfhi(v[k].y);
                af[ch][4] += bflo(v[k].z); af[ch][5] += bfhi(v[k].z);
                af[ch][6] += bflo(v[k].w); af[ch][7] += bfhi(v[k].w);
            }
        }
        int nIt = (dgc + 7) >> 3;
        for (int it = 4; it < nIt; it++) {
            uint2 iw = idxp[it * 2];
            unsigned int jdx[4] = { iw.x & 0xffffu, iw.x >> 16,
                                    iw.y & 0xffffu, iw.y >> 16 };
            uint4 vv[4];
#pragma unroll
            for (int k = 0; k < 4; k++)
                vv[k] = *(const uint4*)(data16 + (size_t)jdx[k] * D + 8 * ln);
#pragma unroll
            for (int k = 0; k < 4; k++) {
                af[k][0] += bflo(vv[k].x); af[k][1] += bfhi(vv[k].x);
                af[k][2] += bflo(vv[k].y); af[k][3] += bfhi(vv[k].y);
                af[k][4] += bflo(vv[k].z); af[k][5] += bfhi(vv[k].z);
                af[k][6] += bflo(vv[k].w); af[k][7] += bfhi(vv[k].w);
            }
        }

        float sv[8];
#pragma unroll
        for (int k = 0; k < 8; k++)
            sv[k] = (af[0][k] + af[1][k]) + (af[2][k] + af[3][k]);
#pragma unroll
        for (int k = 0; k < 8; k++) sv[k] += __shfl_xor(sv[k], 8);   // parities

        if (par == 0) {
            float inv = dg > 0 ? 1.0f / (float)dg : 0.0f;
            float msk = dg > 0 ? 1.0f : 0.0f;
            float4 h0, h1;
            h0.x = (o0.x - sv[0] * inv) * msk; h0.y = (o0.y - sv[1] * inv) * msk;
            h0.z = (o0.z - sv[2] * inv) * msk; h0.w = (o0.w - sv[3] * inv) * msk;
            h1.x = (o1.x - sv[4] * inv) * msk; h1.y = (o1.y - sv[5] * inv) * msk;
            h1.z = (o1.z - sv[6] * inv) * msk; h1.w = (o1.w - sv[7] * inv) * msk;
            union { short8t s; uint4 u; } hv;
            hv.s = pack8(h0, h1);
            st_tile(hb, node, ln * 16, hv.u);
        }
    }

    int w = tid >> 6;
    short8t bfr[4][2];
#pragma unroll
    for (int t = 0; t < 4; t++)
#pragma unroll
        for (int s = 0; s < 2; s++) {
            const float4* wp = (const float4*)(W_lin
                + (size_t)(16 * t + (lane & 15)) * D + (lane >> 4) * 8 + s * 32);
            bfr[t][s] = pack8(wp[0], wp[1]);
        }
    float oldv[4][4];
#pragma unroll
    for (int t = 0; t < 4; t++) {
        int cl = 16 * t + (lane & 15);
#pragma unroll
        for (int j = 0; j < 4; j++) {
            int node = nodeBase + 16 * w + (lane >> 4) * 4 + j;
            oldv[t][j] = out[(size_t)(node < N_NODES ? node : 0) * D + cl];
        }
    }
    __syncthreads();

    f32x4 acc[4] = {{0,0,0,0},{0,0,0,0},{0,0,0,0},{0,0,0,0}};
#pragma unroll
    for (int s = 0; s < 2; s++) {
        short8t a = ld_tile(hb, 16 * w + (lane & 15), (lane >> 4) * 16 + s * 64);
#pragma unroll
        for (int t = 0; t < 4; t++)
            acc[t] = __builtin_amdgcn_mfma_f32_16x16x32_bf16(
                a, bfr[t][s], acc[t], 0, 0, 0);
    }
#pragma unroll
    for (int t = 0; t < 4; t++) {
        int cl = 16 * t + (lane & 15);
#pragma unroll
        for (int j = 0; j < 4; j++) {
            int node = nodeBase + 16 * w + (lane >> 4) * 4 + j;
            if (node < N_NODES) {
                float o = acc[t][j] + oldv[t][j];
                out[(size_t)node * D + cl] = o > 0.f ? o : 0.f;
            }
        }
    }
}

extern "C" void kernel_launch(void* const* d_in, const int* in_sizes, int n_in,
                              void* d_out, int out_size, void* d_ws, size_t ws_size,
                              hipStream_t stream) {
    const float* data  = (const float*)d_in[0];
    const float* merge = (const float*)d_in[1];
    const int*   src   = (const int*)d_in[2];
    const int*   tgt   = (const int*)d_in[3];
    // d_in[4]=W_lin, d_in[5]=b_lin (cancels in lap), d_in[6]=W_tr, d_in[7]=b_tr
    const float* W_lin = (const float*)d_in[4];
    const float* W_tr  = (const float*)d_in[6];
    const float* b_tr  = (const float*)d_in[7];
    float* out = (float*)d_out;

    // Workspace: gCur[1024 i32, flag at 1023] | gPairs[782*1280 u32] (4.0 MB)
    //            | data16[(N+1)*D bf16] (6.4 MB, row 50000 = zeros)
    char* ws = (char*)d_ws;
    size_t o = 0;
    int*            gCur   = (int*)(ws + o);            o += 1024 * 4;
    unsigned int*   gPairs = (unsigned int*)(ws + o);   o += (size_t)KBINS * CCAP64 * 4;
    unsigned short* data16 = (unsigned short*)(ws + o); o += (size_t)(N_NODES + 1) * D * 2;

    // no memset: k1 block 0 zeroes gCur in-kernel (flag handshake)

    k1_kernel<<<K1_BLOCKS, 256, 0, stream>>>(
        data, merge, src, tgt, W_tr, b_tr, data16, gCur, gPairs, out);

    k2_kernel<<<KBINS, 256, 0, stream>>>(
        data, data16, gCur, gPairs, W_lin, out);
}